// Round 2
// baseline (48.822 us; speedup 1.0000x reference)
//
#include <hip/hip_runtime.h>

// Conv4D with separable kernel k4 = K (3x3) ⊗ K (3x3).
// input: (8192, 8,8,8,8) fp32 ; output: (8192, 6,6,6,6) fp32
// Stage 1: conv over last two dims (c,d) -> t (8,8,6,6)
// Stage 2: conv over first two dims (a,b) -> out (6,6,6,6)
// Register-blocked: stage1 reads rows as float4 pairs (ds_read_b128),
// stage2 reads/writes float4 chunks of the 36-wide (c,d) plane.

#define N_SAMPLES 8192
#define IN_PER    4096   // 8*8*8*8
#define T_PER     2304   // 8*8*6*6  laid out [ab][36]
#define OUT_PER   1296   // 6*6*6*6

__global__ __launch_bounds__(256)
void Conv4D_kernel(const float* __restrict__ in,
                   const float* __restrict__ kern,
                   float* __restrict__ out)
{
    __shared__ __align__(16) float x[IN_PER];   // 16 KB
    __shared__ __align__(16) float t[T_PER];    // 9.2 KB

    const int n   = blockIdx.x;
    const int tid = threadIdx.x;

    // 3x3 kernel taps (uniform -> scalar loads)
    float K[9];
#pragma unroll
    for (int i = 0; i < 9; ++i) K[i] = kern[i];

    // --- cooperative load: 4096 floats = 1024 float4, coalesced ---
    const float4* src = reinterpret_cast<const float4*>(in + (size_t)n * IN_PER);
    float4* xv = reinterpret_cast<float4*>(x);
#pragma unroll
    for (int q = 0; q < 4; ++q)
        xv[tid + 256 * q] = src[tid + 256 * q];
    __syncthreads();

    // --- stage 1: 384 tasks = (ab 0..63) x (c 0..5) ---
    // each task: read rows c..c+2 of x[ab] as 6 float4, produce 6 d-outputs
    for (int tk = tid; tk < 384; tk += 256) {
        const int ab = tk / 6;
        const int c  = tk % 6;
        const float4* xr = reinterpret_cast<const float4*>(x + ab * 64 + c * 8);
        const float4 q0 = xr[0], q1 = xr[1];   // row c
        const float4 q2 = xr[2], q3 = xr[3];   // row c+1
        const float4 q4 = xr[4], q5 = xr[5];   // row c+2
        const float X0[8] = {q0.x,q0.y,q0.z,q0.w, q1.x,q1.y,q1.z,q1.w};
        const float X1[8] = {q2.x,q2.y,q2.z,q2.w, q3.x,q3.y,q3.z,q3.w};
        const float X2[8] = {q4.x,q4.y,q4.z,q4.w, q5.x,q5.y,q5.z,q5.w};
        float o[6];
#pragma unroll
        for (int d = 0; d < 6; ++d) {
            float acc = 0.f;
#pragma unroll
            for (int l = 0; l < 3; ++l) {
                acc = fmaf(X0[d + l], K[0 + l], acc);
                acc = fmaf(X1[d + l], K[3 + l], acc);
                acc = fmaf(X2[d + l], K[6 + l], acc);
            }
            o[d] = acc;
        }
        float2* tw = reinterpret_cast<float2*>(t + ab * 36 + c * 6);
        tw[0] = make_float2(o[0], o[1]);
        tw[1] = make_float2(o[2], o[3]);
        tw[2] = make_float2(o[4], o[5]);
    }
    __syncthreads();

    // --- stage 2: 324 tasks = (ab6 = a*6+b, 0..35) x (chunk 0..8 of 36) ---
    // each task: 9 float4 LDS reads (neighbor ab rows), 1 float4 global store
    float* dst = out + (size_t)n * OUT_PER;
    for (int o4 = tid; o4 < 324; o4 += 256) {
        const int ab6 = o4 / 9;
        const int ch  = o4 % 9;
        const int a   = ab6 / 6;
        const int b   = ab6 % 6;
        float4 acc = make_float4(0.f, 0.f, 0.f, 0.f);
#pragma unroll
        for (int i = 0; i < 3; ++i)
#pragma unroll
            for (int j = 0; j < 3; ++j) {
                const float4 v = *reinterpret_cast<const float4*>(
                    t + ((a + i) * 8 + (b + j)) * 36 + ch * 4);
                const float kv = K[i * 3 + j];
                acc.x = fmaf(v.x, kv, acc.x);
                acc.y = fmaf(v.y, kv, acc.y);
                acc.z = fmaf(v.z, kv, acc.z);
                acc.w = fmaf(v.w, kv, acc.w);
            }
        *reinterpret_cast<float4*>(dst + ab6 * 36 + ch * 4) = acc;
    }
}

extern "C" void kernel_launch(void* const* d_in, const int* in_sizes, int n_in,
                              void* d_out, int out_size, void* d_ws, size_t ws_size,
                              hipStream_t stream) {
    const float* in   = (const float*)d_in[0];
    const float* kern = (const float*)d_in[1];
    float* out        = (float*)d_out;

    Conv4D_kernel<<<N_SAMPLES, 256, 0, stream>>>(in, kern, out);
}

// Round 3
// 31.101 us; speedup vs baseline: 1.5698x; 1.5698x over previous
//
#include <hip/hip_runtime.h>

// Conv4D with separable kernel k4 = K (3x3) ⊗ K (3x3).
// input: (8192, 8,8,8,8) fp32 ; output: (8192, 6,6,6,6) fp32
// Stage 1: conv over (c,d) -> t (8,8,6,6), read DIRECT from global (L1/L2 reuse)
// Stage 2: conv over (a,b) -> out, t in LDS, imm-offset ds_read_b64 only.

#define IN_PER    4096   // 8*8*8*8
#define OUT_PER   1296   // 6*6*6*6
#define N_SAMPLES 8192

__global__ __launch_bounds__(256)
void Conv4D_kernel(const float* __restrict__ in,
                   const float* __restrict__ kern,
                   float* __restrict__ out)
{
    __shared__ __align__(16) float t[64 * 36];   // 9.2 KB, [ab][cd=36]

    const int n   = blockIdx.x;
    const int tid = threadIdx.x;

    float K[9];
#pragma unroll
    for (int i = 0; i < 9; ++i) K[i] = kern[i];

    const float* xg = in + (size_t)n * IN_PER;

    // --- stage 1: 384 tasks = (ab 0..63) x (c 0..5), direct-from-global ---
    // each task reads rows c..c+2 of x[ab] (6 x dwordx4) and writes 6 t values
#pragma unroll
    for (int r = 0; r < 2; ++r) {
        const int tk = tid + 256 * r;
        if (tk < 384) {
            const int ab = tk / 6;
            const int c  = tk % 6;
            const float* xp = xg + ab * 64 + c * 8;
            const float4 q0 = *reinterpret_cast<const float4*>(xp);
            const float4 q1 = *reinterpret_cast<const float4*>(xp + 4);
            const float4 q2 = *reinterpret_cast<const float4*>(xp + 8);
            const float4 q3 = *reinterpret_cast<const float4*>(xp + 12);
            const float4 q4 = *reinterpret_cast<const float4*>(xp + 16);
            const float4 q5 = *reinterpret_cast<const float4*>(xp + 20);
            const float X0[8] = {q0.x,q0.y,q0.z,q0.w, q1.x,q1.y,q1.z,q1.w};
            const float X1[8] = {q2.x,q2.y,q2.z,q2.w, q3.x,q3.y,q3.z,q3.w};
            const float X2[8] = {q4.x,q4.y,q4.z,q4.w, q5.x,q5.y,q5.z,q5.w};
            float o[6];
#pragma unroll
            for (int d = 0; d < 6; ++d) {
                float acc = 0.f;
#pragma unroll
                for (int l = 0; l < 3; ++l) {
                    acc = fmaf(X0[d + l], K[0 + l], acc);
                    acc = fmaf(X1[d + l], K[3 + l], acc);
                    acc = fmaf(X2[d + l], K[6 + l], acc);
                }
                o[d] = acc;
            }
            float2* tw = reinterpret_cast<float2*>(t + ab * 36 + c * 6);
            tw[0] = make_float2(o[0], o[1]);
            tw[1] = make_float2(o[2], o[3]);
            tw[2] = make_float2(o[4], o[5]);
        }
    }
    __syncthreads();

    // --- stage 2: 216 tasks = (a 0..5, b 0..5, c 0..5), one per thread ---
    // 27 ds_read_b64 with immediate offsets; 3 float2 global stores
    if (tid < 216) {
        const int c   = tid % 6;
        const int ab6 = tid / 6;
        const int b   = ab6 % 6;
        const int a   = ab6 / 6;
        const float* tp = t + (a * 8 + b) * 36 + c * 6;
        float a0 = 0.f, a1 = 0.f, a2 = 0.f, a3 = 0.f, a4 = 0.f, a5 = 0.f;
#pragma unroll
        for (int i = 0; i < 3; ++i)
#pragma unroll
            for (int j = 0; j < 3; ++j) {
                const float kv = K[i * 3 + j];
                const float* rp = tp + (i * 8 + j) * 36;   // imm offset after unroll
                const float2 v0 = *reinterpret_cast<const float2*>(rp);
                const float2 v1 = *reinterpret_cast<const float2*>(rp + 2);
                const float2 v2 = *reinterpret_cast<const float2*>(rp + 4);
                a0 = fmaf(v0.x, kv, a0);
                a1 = fmaf(v0.y, kv, a1);
                a2 = fmaf(v1.x, kv, a2);
                a3 = fmaf(v1.y, kv, a3);
                a4 = fmaf(v2.x, kv, a4);
                a5 = fmaf(v2.y, kv, a5);
            }
        float* dst = out + (size_t)n * OUT_PER + (a * 6 + b) * 36 + c * 6;
        float2* dv = reinterpret_cast<float2*>(dst);
        dv[0] = make_float2(a0, a1);
        dv[1] = make_float2(a2, a3);
        dv[2] = make_float2(a4, a5);
    }
}

extern "C" void kernel_launch(void* const* d_in, const int* in_sizes, int n_in,
                              void* d_out, int out_size, void* d_ws, size_t ws_size,
                              hipStream_t stream) {
    const float* in   = (const float*)d_in[0];
    const float* kern = (const float*)d_in[1];
    float* out        = (float*)d_out;

    Conv4D_kernel<<<N_SAMPLES, 256, 0, stream>>>(in, kern, out);
}

// Round 4
// 31.074 us; speedup vs baseline: 1.5712x; 1.0009x over previous
//
#include <hip/hip_runtime.h>

// Conv4D with separable kernel k4 = K (3x3) ⊗ K (3x3).
// input: (8192, 8,8,8,8) fp32 ; output: (8192, 6,6,6,6) fp32
// Stage 1: conv over (c,d) -> t (8,8,6,6), read DIRECT from global (L1/L2 reuse)
// Stage 2: conv over (a,b) -> ob in LDS, imm-offset ds_read_b64 only.
// Epilogue: coalesced float4 stores of ob (324 dwordx4 per block).

#define IN_PER    4096   // 8*8*8*8
#define OUT_PER   1296   // 6*6*6*6
#define N_SAMPLES 8192

__global__ __launch_bounds__(256)
void Conv4D_kernel(const float* __restrict__ in,
                   const float* __restrict__ kern,
                   float* __restrict__ out)
{
    __shared__ __align__(16) float t[64 * 36];    // 9.2 KB, [ab][cd=36]
    __shared__ __align__(16) float ob[OUT_PER];   // 5.2 KB, staged output

    const int n   = blockIdx.x;
    const int tid = threadIdx.x;

    float K[9];
#pragma unroll
    for (int i = 0; i < 9; ++i) K[i] = kern[i];

    const float* xg = in + (size_t)n * IN_PER;

    // --- stage 1: 384 tasks = (ab 0..63) x (c 0..5), direct-from-global ---
#pragma unroll
    for (int r = 0; r < 2; ++r) {
        const int tk = tid + 256 * r;
        if (tk < 384) {
            const int ab = tk / 6;
            const int c  = tk % 6;
            const float* xp = xg + ab * 64 + c * 8;
            const float4 q0 = *reinterpret_cast<const float4*>(xp);
            const float4 q1 = *reinterpret_cast<const float4*>(xp + 4);
            const float4 q2 = *reinterpret_cast<const float4*>(xp + 8);
            const float4 q3 = *reinterpret_cast<const float4*>(xp + 12);
            const float4 q4 = *reinterpret_cast<const float4*>(xp + 16);
            const float4 q5 = *reinterpret_cast<const float4*>(xp + 20);
            const float X0[8] = {q0.x,q0.y,q0.z,q0.w, q1.x,q1.y,q1.z,q1.w};
            const float X1[8] = {q2.x,q2.y,q2.z,q2.w, q3.x,q3.y,q3.z,q3.w};
            const float X2[8] = {q4.x,q4.y,q4.z,q4.w, q5.x,q5.y,q5.z,q5.w};
            float o[6];
#pragma unroll
            for (int d = 0; d < 6; ++d) {
                float acc = 0.f;
#pragma unroll
                for (int l = 0; l < 3; ++l) {
                    acc = fmaf(X0[d + l], K[0 + l], acc);
                    acc = fmaf(X1[d + l], K[3 + l], acc);
                    acc = fmaf(X2[d + l], K[6 + l], acc);
                }
                o[d] = acc;
            }
            float2* tw = reinterpret_cast<float2*>(t + ab * 36 + c * 6);
            tw[0] = make_float2(o[0], o[1]);
            tw[1] = make_float2(o[2], o[3]);
            tw[2] = make_float2(o[4], o[5]);
        }
    }
    __syncthreads();

    // --- stage 2: 216 tasks = (a 0..5, b 0..5, c 0..5), one per thread ---
    // 27 ds_read_b64 with immediate offsets; results staged to LDS ob[]
    if (tid < 216) {
        const int c   = tid % 6;
        const int ab6 = tid / 6;
        const int b   = ab6 % 6;
        const int a   = ab6 / 6;
        const float* tp = t + (a * 8 + b) * 36 + c * 6;
        float a0 = 0.f, a1 = 0.f, a2 = 0.f, a3 = 0.f, a4 = 0.f, a5 = 0.f;
#pragma unroll
        for (int i = 0; i < 3; ++i)
#pragma unroll
            for (int j = 0; j < 3; ++j) {
                const float kv = K[i * 3 + j];
                const float* rp = tp + (i * 8 + j) * 36;   // imm offset after unroll
                const float2 v0 = *reinterpret_cast<const float2*>(rp);
                const float2 v1 = *reinterpret_cast<const float2*>(rp + 2);
                const float2 v2 = *reinterpret_cast<const float2*>(rp + 4);
                a0 = fmaf(v0.x, kv, a0);
                a1 = fmaf(v0.y, kv, a1);
                a2 = fmaf(v1.x, kv, a2);
                a3 = fmaf(v1.y, kv, a3);
                a4 = fmaf(v2.x, kv, a4);
                a5 = fmaf(v2.y, kv, a5);
            }
        // ob offset = ((a*6+b)*36 + c*6) = tid*6  (contiguous)
        float2* ov = reinterpret_cast<float2*>(ob + tid * 6);
        ov[0] = make_float2(a0, a1);
        ov[1] = make_float2(a2, a3);
        ov[2] = make_float2(a4, a5);
    }
    __syncthreads();

    // --- epilogue: 324 fully-coalesced dwordx4 stores ---
    const float4* obv = reinterpret_cast<const float4*>(ob);
    float4* dst = reinterpret_cast<float4*>(out + (size_t)n * OUT_PER);
    dst[tid] = obv[tid];                       // quads 0..255
    if (tid < 68) dst[256 + tid] = obv[256 + tid];  // quads 256..323
}

extern "C" void kernel_launch(void* const* d_in, const int* in_sizes, int n_in,
                              void* d_out, int out_size, void* d_ws, size_t ws_size,
                              hipStream_t stream) {
    const float* in   = (const float*)d_in[0];
    const float* kern = (const float*)d_in[1];
    float* out        = (float*)d_out;

    Conv4D_kernel<<<N_SAMPLES, 256, 0, stream>>>(in, kern, out);
}